// Round 8
// baseline (35.010 us; speedup 1.0000x reference)
//
#include <hip/hip_runtime.h>
#include <hip/hip_bf16.h>
#include <hip/hip_fp16.h>

typedef __attribute__((ext_vector_type(8))) short bf16x8;
typedef __attribute__((ext_vector_type(4))) float f32x4;
typedef __attribute__((ext_vector_type(4))) int   i32x4;

#define O_TOTAL 8192
#define I_TOTAL 8192
#define NWAVES  8
#define NSS     32                                 // supersteps: 256 k-blocks / 8 waves
#define ROW_I32 (I_TOTAL / 2)                      // 4096 int32 per weight row
#define NBLOCKS 256                                // 32-wide k-blocks per row
#define DEPTH   4                                  // LDS pipeline depth

typedef __attribute__((address_space(1))) const void GASV;
typedef __attribute__((address_space(3))) void LASV;

static __device__ __forceinline__ short f2bf(float f) {
    union { __hip_bfloat16 b; short s; } u;
    u.b = __float2bfloat16(f);
    return u.s;
}

static __device__ __forceinline__ float bf2f(unsigned short s) {
    union { unsigned int u; float f; } v;
    v.u = ((unsigned int)s) << 16;
    return v.f;
}

// ---- kernel 0: x fp32 -> bf16 bits, once per launch ----
__global__ __launch_bounds__(256)
void xcvt_kernel(const float* __restrict__ x, short* __restrict__ xb)
{
    const int i = (blockIdx.x * 256 + threadIdx.x) * 4;   // 4 elems/thread
    f32x4 v = *(const f32x4*)(x + i);
    union { short s[4]; long long q; } p;
    p.s[0] = f2bf(v[0]); p.s[1] = f2bf(v[1]); p.s[2] = f2bf(v[2]); p.s[3] = f2bf(v[3]);
    *(long long*)(xb + i) = p.q;
}

// ---- kernel 1: main MFMA kernel, depth-4 counted-vmcnt pipeline ----
__global__ __launch_bounds__(512, 4)
void linq4_kernel(const short* __restrict__ xb,    // x as bf16 bits [16][8192]
                  const int* __restrict__ wq,
                  const void* __restrict__ wn,     // norm buffer, dtype sniffed at runtime
                  const float* __restrict__ bias,
                  float* __restrict__ out)
{
    const int tid  = threadIdx.x;
    const int w    = tid >> 6;             // wave 0..7
    const int lane = tid & 63;
    const int otile = blockIdx.x;          // 0..511 : 16 output rows each
    const int o0   = otile * 16;
    // per-block circular k-phase: decorrelates instantaneous column offsets
    const int phase = (otile * 7) & (NSS - 1);

    // ---- sniff the norm buffer's storage format ----
    const unsigned int* w32 = (const unsigned int*)wn;
    int cntLo = 0, cntHi = 0;
    #pragma unroll
    for (int i = 0; i < 16; ++i) {
        unsigned int ww = w32[i];
        unsigned int lo = ww & 0xFFFFu, hi = ww >> 16;
        if (lo >= 0x3980u && lo < 0x3F80u) cntLo++;
        if (hi >= 0x3C00u) cntHi++;
    }
    const int fmt = (cntLo >= 12) ? 1 : (cntHi >= 12 ? 0 : 2); // 0=f32 1=bf16 2=f16

    // ---- LDS ----
    __shared__ int   w_lds[DEPTH][2048];   // 4 x 8KB
    __shared__ short x_lds[DEPTH][4096];   // 4 x 8KB
    __shared__ float nlds[NBLOCKS];        // 1KB
    __shared__ float red[NWAVES][256];     // 8KB

    if (tid < NBLOCKS) {
        const int idx = otile * NBLOCKS + tid;
        float nf;
        if (fmt == 0)      nf = ((const float*)wn)[idx];
        else if (fmt == 1) nf = bf2f(((const unsigned short*)wn)[idx]);
        else               nf = __half2float(((const __half*)wn)[idx]);
        nlds[tid] = nf;
    }

    // ---- staging geometry (per wave): rows {2w,2w+1}, 512B runs, pre-swizzled src ----
    const int r_st  = 2 * w + (lane >> 5);
    const int jj    = (lane & 31) ^ (r_st & 7);    // involution pre-swizzle
    const int* gw_base   = wq + (size_t)(o0 + r_st) * ROW_I32 + jj * 4;   // +Sp*128
    const short* gx_base = xb + (size_t)r_st * I_TOTAL + jj * 8;          // +Sp*256

    // ---- consume geometry (per lane) ----
    const int col = lane & 15;             // B col / A row (m)
    const int kg  = lane >> 4;             // 0..3
    const int j   = w * 4 + kg;            // 16B unit consumed (0..31)
    const int t   = j ^ (col & 7);         // swizzled slot
    const int ldsoff = col * 128 + t * 4;  // int32 index within a W buffer
    const int xldoff = col * 256 + t * 8;  // short index within an x buffer

    f32x4 acc = {0.f, 0.f, 0.f, 0.f};

    // ---- prologue: issue stages 0,1,2 (6 loads/wave outstanding) ----
    #pragma unroll
    for (int s = 0; s < DEPTH - 1; ++s) {
        const int Sp = (s + phase) & (NSS - 1);
        __builtin_amdgcn_global_load_lds((GASV*)(gw_base + Sp * 128),
                                         (LASV*)(&w_lds[s][w * 256]), 16, 0, 0);
        __builtin_amdgcn_global_load_lds((GASV*)(gx_base + Sp * 256),
                                         (LASV*)(&x_lds[s][w * 512]), 16, 0, 0);
    }
    // nlds stores must be visible after the first barrier
    asm volatile("s_waitcnt lgkmcnt(0)" ::: "memory");

    for (int T = 0; T < NSS; ++T) {
        // counted wait: stage T landed; later stages stay in flight (never drain to 0
        // in steady state -- the T4 lesson)
        if (T <= NSS - 3)      asm volatile("s_waitcnt vmcnt(4)" ::: "memory");
        else if (T == NSS - 2) asm volatile("s_waitcnt vmcnt(2)" ::: "memory");
        else                   asm volatile("s_waitcnt vmcnt(0)" ::: "memory");
        // all waves' stage-T writes visible; all waves done reading buffer (T-1)&3
        __builtin_amdgcn_s_barrier();

        // issue stage T+3 into buffer (T+3)&3 == (T-1)&3 (proven free by the barrier)
        if (T + DEPTH - 1 < NSS) {
            const int s   = T + DEPTH - 1;
            const int Sp  = (s + phase) & (NSS - 1);
            const int buf = s & (DEPTH - 1);
            __builtin_amdgcn_global_load_lds((GASV*)(gw_base + Sp * 128),
                                             (LASV*)(&w_lds[buf][w * 256]), 16, 0, 0);
            __builtin_amdgcn_global_load_lds((GASV*)(gx_base + Sp * 256),
                                             (LASV*)(&x_lds[buf][w * 512]), 16, 0, 0);
        }

        // consume buffer T&3: one 16x16x32 MFMA for k-block (Sp*8 + w)
        const int cur = T & (DEPTH - 1);
        const int Sp  = (T + phase) & (NSS - 1);
        i32x4  pv = *(const i32x4*)(&w_lds[cur][ldsoff]);
        bf16x8 xa = *(const bf16x8*)(&x_lds[cur][xldoff]);
        const float nf = nlds[Sp * 8 + w];
        const float sc = nf * (2.0f / 15.0f);

        bf16x8 bfrag;
        #pragma unroll
        for (int c = 0; c < 4; ++c) {
            int v = pv[c];
            float wl = (float)(v & 15)        * sc - nf;
            float wh = (float)((v >> 4) & 15) * sc - nf;
            bfrag[2*c]   = f2bf(wl);
            bfrag[2*c+1] = f2bf(wh);
        }

        acc = __builtin_amdgcn_mfma_f32_16x16x32_bf16(xa, bfrag, acc, 0, 0, 0);
    }

    // ---- cross-wave K reduction ----
    *(f32x4*)&red[w][lane * 4] = acc;
    __syncthreads();

    if (tid < 256) {
        float s = 0.f;
        #pragma unroll
        for (int q = 0; q < NWAVES; ++q) s += red[q][tid];
        const int l = tid >> 2;            // original lane
        const int r = tid & 3;             // acc register index
        const int m  = ((l >> 4) << 2) + r;    // C row = (lane>>4)*4 + reg
        const int oc = o0 + (l & 15);          // C col = lane&15
        out[(size_t)m * O_TOTAL + oc] = s + bias[oc];
    }
}

extern "C" void kernel_launch(void* const* d_in, const int* in_sizes, int n_in,
                              void* d_out, int out_size, void* d_ws, size_t ws_size,
                              hipStream_t stream) {
    const float* x    = (const float*)d_in[0];
    const int*   wq   = (const int*)d_in[1];
    const void*  wn   = (const void*)d_in[2];   // dtype sniffed on device
    const float* bias = (const float*)d_in[3];
    float* out = (float*)d_out;
    short* xb  = (short*)d_ws;                  // 16*8192 bf16 = 256 KB scratch

    // stage 0: convert x to bf16
    hipLaunchKernelGGL(xcvt_kernel, dim3(16 * I_TOTAL / 4 / 256), dim3(256), 0, stream, x, xb);

    // stage 1: main kernel — depth-4 counted-vmcnt pipeline
    hipLaunchKernelGGL(linq4_kernel, dim3(O_TOTAL / 16), dim3(512), 0, stream,
                       (const short*)xb, wq, wn, bias, out);
}